// Round 1
// 629.385 us; speedup vs baseline: 1.2702x; 1.2702x over previous
//
#include <hip/hip_runtime.h>
#include <stdint.h>

typedef float f32x4 __attribute__((ext_vector_type(4)));
typedef int   i32x4 __attribute__((ext_vector_type(4)));
typedef int   i32x8 __attribute__((ext_vector_type(8)));

#define AS1 __attribute__((address_space(1)))
#define AS3 __attribute__((address_space(3)))

__device__ __forceinline__ void async_copy16(const void* g, void* l) {
    __builtin_amdgcn_global_load_lds((AS1 void*)(g), (AS3 void*)(l), 16, 0, 0);
}

// ---------------------------------------------------------------- init
__global__ void init_kernel(unsigned* amaxs) {
    if (threadIdx.x < 2) amaxs[threadIdx.x] = 0u;
}

// ---------------------------------------------------------------- amax (both tensors, 1 atomic/block)
__global__ __launch_bounds__(256) void amax2_kernel(
    const float4* __restrict__ x0, int n40,
    const float4* __restrict__ x1, int n41,
    int nb0, unsigned* __restrict__ amaxs)
{
    __shared__ float red[4];
    const float4* x; int n4; unsigned* dst; int bid, nb;
    if ((int)blockIdx.x < nb0) {
        x = x0; n4 = n40; dst = amaxs + 0; bid = blockIdx.x; nb = nb0;
    } else {
        x = x1; n4 = n41; dst = amaxs + 1; bid = blockIdx.x - nb0; nb = gridDim.x - nb0;
    }
    float m = 0.0f;
    int idx = bid * 256 + threadIdx.x;
    int stride = nb * 256;
    for (int i = idx; i < n4; i += stride) {
        float4 v = x[i];
        m = fmaxf(fmaxf(m, fmaxf(fabsf(v.x), fabsf(v.y))),
                  fmaxf(fabsf(v.z), fabsf(v.w)));
    }
#pragma unroll
    for (int off = 32; off > 0; off >>= 1)
        m = fmaxf(m, __shfl_down(m, off));
    if ((threadIdx.x & 63) == 0) red[threadIdx.x >> 6] = m;
    __syncthreads();
    if (threadIdx.x == 0) {
        m = fmaxf(fmaxf(red[0], red[1]), fmaxf(red[2], red[3]));
        atomicMax(dst, __float_as_uint(m));
    }
}

// ---------------------------------------------------------------- quantize (both tensors)
__global__ __launch_bounds__(256) void quant2_kernel(
    const float4* __restrict__ x0, int n40,
    const float4* __restrict__ x1, int n41,
    int nb0, const unsigned* __restrict__ amaxs,
    unsigned* __restrict__ q0, unsigned* __restrict__ q1)
{
    const float4* x; int n4; unsigned* q; int bid, nb; float amax;
    if ((int)blockIdx.x < nb0) {
        x = x0; n4 = n40; q = q0; bid = blockIdx.x; nb = nb0;
        amax = __uint_as_float(amaxs[0]);
    } else {
        x = x1; n4 = n41; q = q1; bid = blockIdx.x - nb0; nb = gridDim.x - nb0;
        amax = __uint_as_float(amaxs[1]);
    }
    const float s = 448.0f / fmaxf(amax, 1e-12f);
    int idx = bid * 256 + threadIdx.x;
    int stride = nb * 256;
    for (int i = idx; i < n4; i += stride) {
        float4 v = x[i];
        float a = fminf(fmaxf(v.x * s, -448.0f), 448.0f);
        float b = fminf(fmaxf(v.y * s, -448.0f), 448.0f);
        float c = fminf(fmaxf(v.z * s, -448.0f), 448.0f);
        float d = fminf(fmaxf(v.w * s, -448.0f), 448.0f);
        int p = 0;
        p = __builtin_amdgcn_cvt_pk_fp8_f32(a, b, p, false);
        p = __builtin_amdgcn_cvt_pk_fp8_f32(c, d, p, true);
        q[i] = (unsigned)p;
    }
}

// ---------------------------------------------------------------- GEMM
// C[m,n] = sum_k A[m,k]*B[n,k]  (fp8 e4m3, K-major)  * scale + bias[n]
//
// 256x256 tile, 8 waves (2x4), per-wave C = 128x64 (8x4 16x16 frags).
// MFMA: mfma_scale_f32_16x16x128_f8f6f4 with e8m0 scales = 127 (x1.0):
//   bit-identical fp8 dot at 2x the non-scaled 16x16x32 rate.
//   A/B frag layout: lane holds 32 CONTIGUOUS k bytes, k-block = lane>>4.
// LDS: ring of 9 stage-steps x (A 8KB + B 8KB) = 144 KiB; step = 32 k-cols.
//   Placement swizzle: 16B unit(r,h) = (2r+h) ^ (u&3)  -> every frag
//   ds_read_b128 is at the 8-cycle wave64 bank floor; global source is
//   pre-swizzled so global_load_lds dest stays linear (base + lane*16).
// Pipeline: 4 phases/K-step {ds_read | 1 stage-step issue | bar | MFMA | bar},
//   boundary s_waitcnt vmcnt(2) (never 0 mid-loop), issue runs ~3 steps ahead.
#define RING 9
#define STEPB 8192

__global__ __launch_bounds__(512, 2) void gemm_fp8(
    const uint8_t* __restrict__ qA,
    const uint8_t* __restrict__ qB,
    const float*   __restrict__ bias,
    const unsigned* __restrict__ amaxs,
    float* __restrict__ out,
    int M, int N, int K)
{
    __shared__ uint8_t lds[2 * RING * STEPB];   // 144 KiB

    const int tid  = threadIdx.x;
    const int lane = tid & 63;
    const int wave = tid >> 6;
    const int wm   = wave >> 2;        // 0..1  (row half)
    const int wn   = wave & 3;         // 0..3  (col quarter)

    // XCD-aware bijective swizzle (grid = 688 = 8*86): each XCD gets a
    // contiguous run = 2 full mtile rows -> A panel L2-resident.
    const int ntiles = N >> 8;                       // 43
    const int per    = (int)gridDim.x >> 3;          // 86
    const int swz    = ((int)blockIdx.x & 7) * per + ((int)blockIdx.x >> 3);
    const int mtile  = swz / ntiles;
    const int ntile  = swz - mtile * ntiles;

    const int li   = lane & 15;
    const int lj   = lane >> 4;        // k-block of this lane's MFMA operand
    const int jx16 = lj << 4;
    const int ai32 = li << 5;

    uint8_t* ldsA = lds;
    uint8_t* ldsB = lds + RING * STEPB;
    const int wl = wave << 10;         // wave-uniform LDS slice base

    const uint8_t* gApan = qA + (size_t)(mtile << 8) * K;
    const uint8_t* gBpan = qB + (size_t)(ntile << 8) * K;

    // stage source pre-swizzle: thread tid must load the chunk (r,h) whose
    // swizzled unit index equals tid:  2r+h = tid ^ (u&3)
    int off[4];
#pragma unroll
    for (int g = 0; g < 4; ++g) {
        int x = tid ^ g;
        off[g] = (x >> 1) * K + (x & 1) * 16;
    }

#define STAGE(u_, su_, g_) do {                                              \
        async_copy16(gApan + (off[(g_)] + ((u_) << 5)),                      \
                     ldsA + ((su_) * STEPB + wl));                           \
        async_copy16(gBpan + (off[(g_)] + ((u_) << 5)),                      \
                     ldsB + ((su_) * STEPB + wl));                           \
    } while (0)

    // frag read: two b128 at (32*row+16h)^jx16 within this lane's k-block slot
#define LDFRAG(dst_, base_, rowc_) do {                                      \
        int _o = (((rowc_) + ai32) ^ jx16);                                  \
        i32x4 _lo = *(const i32x4*)((base_) + _o);                           \
        i32x4 _hi = *(const i32x4*)((base_) + (_o ^ 16));                    \
        (dst_) = __builtin_shufflevector(_lo, _hi, 0, 1, 2, 3, 4, 5, 6, 7);  \
    } while (0)

#define MFMA(acc_, a_, b_)                                                   \
    (acc_) = __builtin_amdgcn_mfma_scale_f32_16x16x128_f8f6f4(               \
        (a_), (b_), (acc_), 0, 0, 0, 0x7F7F7F7F, 0, 0x7F7F7F7F)

    // prologue: stage steps 0..4 (slots 0..4), need 0..3 for t=0
    STAGE(0, 0, 0); STAGE(1, 1, 1); STAGE(2, 2, 2); STAGE(3, 3, 3); STAGE(4, 4, 0);
    asm volatile("s_waitcnt vmcnt(2)" ::: "memory");
    __builtin_amdgcn_s_barrier();
    asm volatile("" ::: "memory");

    f32x4 acc[8][4] = {};
    i32x8 afr[4], bfr[4];

    const int rAc = wm << 12;          // 32 * (wm*128)
    const int rBc = wn << 11;          // 32 * (wn*64)
    const int NSTEP = K >> 7;          // 32 MFMA K-steps
    const int NSU   = K >> 5;          // 128 stage-steps

    int s4 = 0;                        // (4t) % RING
#pragma unroll 1
    for (int t = 0; t < NSTEP; ++t) {
        int sl = s4 + lj; if (sl >= RING) sl -= RING;   // per-lane ring slot
        const uint8_t* rdA = ldsA + sl * STEPB;
        const uint8_t* rdB = ldsB + sl * STEPB;
        const int u0 = (t << 2) + 5;

        // ---- phase 0: read A(mq0) + B0,B1 ; stage u0 ; mfma (mq0 x nq0)
        LDFRAG(afr[0], rdA, rAc + 0 * 512);
        LDFRAG(afr[1], rdA, rAc + 1 * 512);
        LDFRAG(afr[2], rdA, rAc + 2 * 512);
        LDFRAG(afr[3], rdA, rAc + 3 * 512);
        LDFRAG(bfr[0], rdB, rBc + 0 * 512);
        LDFRAG(bfr[1], rdB, rBc + 1 * 512);
        if (u0 < NSU) { int su = s4 + 5; if (su >= RING) su -= RING; STAGE(u0, su, 1); }
        __builtin_amdgcn_s_barrier();
        __builtin_amdgcn_s_setprio(1);
#pragma unroll
        for (int fi = 0; fi < 4; ++fi) {
            MFMA(acc[fi][0], afr[fi], bfr[0]);
            MFMA(acc[fi][1], afr[fi], bfr[1]);
        }
        __builtin_amdgcn_s_setprio(0);
        __builtin_amdgcn_s_barrier();

        // ---- phase 1: read B2,B3 ; stage u0+1 ; mfma (mq0 x nq1)
        LDFRAG(bfr[2], rdB, rBc + 2 * 512);
        LDFRAG(bfr[3], rdB, rBc + 3 * 512);
        if (u0 + 1 < NSU) { int su = s4 + 6; if (su >= RING) su -= RING; STAGE(u0 + 1, su, 2); }
        __builtin_amdgcn_s_barrier();
        __builtin_amdgcn_s_setprio(1);
#pragma unroll
        for (int fi = 0; fi < 4; ++fi) {
            MFMA(acc[fi][2], afr[fi], bfr[2]);
            MFMA(acc[fi][3], afr[fi], bfr[3]);
        }
        __builtin_amdgcn_s_setprio(0);
        __builtin_amdgcn_s_barrier();

        // ---- phase 2: read A(mq1) ; stage u0+2 ; mfma (mq1 x nq1)
        LDFRAG(afr[0], rdA, rAc + 2048 + 0 * 512);
        LDFRAG(afr[1], rdA, rAc + 2048 + 1 * 512);
        LDFRAG(afr[2], rdA, rAc + 2048 + 2 * 512);
        LDFRAG(afr[3], rdA, rAc + 2048 + 3 * 512);
        if (u0 + 2 < NSU) { int su = s4 + 7; if (su >= RING) su -= RING; STAGE(u0 + 2, su, 3); }
        __builtin_amdgcn_s_barrier();
        __builtin_amdgcn_s_setprio(1);
#pragma unroll
        for (int fi = 0; fi < 4; ++fi) {
            MFMA(acc[4 + fi][2], afr[fi], bfr[2]);
            MFMA(acc[4 + fi][3], afr[fi], bfr[3]);
        }
        __builtin_amdgcn_s_setprio(0);
        __builtin_amdgcn_s_barrier();

        // ---- phase 3: stage u0+3 ; mfma (mq1 x nq0)
        if (u0 + 3 < NSU) { int su = s4 + 8; if (su >= RING) su -= RING; STAGE(u0 + 3, su, 0); }
        __builtin_amdgcn_s_barrier();
        __builtin_amdgcn_s_setprio(1);
#pragma unroll
        for (int fi = 0; fi < 4; ++fi) {
            MFMA(acc[4 + fi][0], afr[fi], bfr[0]);
            MFMA(acc[4 + fi][1], afr[fi], bfr[1]);
        }
        __builtin_amdgcn_s_setprio(0);

        // ---- step boundary: counted drain (next step's 4 stage-steps landed,
        //      newest stage-step may stay in flight), then publish
        if (t == NSTEP - 2)      asm volatile("s_waitcnt vmcnt(0)" ::: "memory");
        else if (t <  NSTEP - 2) asm volatile("s_waitcnt vmcnt(2)" ::: "memory");
        __builtin_amdgcn_s_barrier();
        asm volatile("" ::: "memory");

        s4 += 4; if (s4 >= RING) s4 -= RING;
    }

    // --- epilogue
    const float amax_a = fmaxf(__uint_as_float(amaxs[0]), 1e-12f);
    const float amax_w = fmaxf(__uint_as_float(amaxs[1]), 1e-12f);
    const float scale = (amax_a * amax_w) * (1.0f / (448.0f * 448.0f));

    const int row0 = (mtile << 8) + (wm << 7) + (lj << 2);
    const int col0 = (ntile << 8) + (wn << 6) + li;
#pragma unroll
    for (int fj = 0; fj < 4; ++fj) {
        const int col = col0 + fj * 16;
        const float bv = bias[col];
#pragma unroll
        for (int fi = 0; fi < 8; ++fi) {
            const int row = row0 + fi * 16;
#pragma unroll
            for (int r = 0; r < 4; ++r)
                out[(size_t)(row + r) * N + col] = acc[fi][fj][r] * scale + bv;
        }
    }
#undef STAGE
#undef LDFRAG
#undef MFMA
}

// ---------------------------------------------------------------- launch
extern "C" void kernel_launch(void* const* d_in, const int* in_sizes, int n_in,
                              void* d_out, int out_size, void* d_ws, size_t ws_size,
                              hipStream_t stream) {
    const float* inp  = (const float*)d_in[0];
    const float* wgt  = (const float*)d_in[1];
    const float* bias = (const float*)d_in[2];
    float* out = (float*)d_out;

    const int N = in_sizes[2];              // 11008
    const int K = in_sizes[1] / N;          // 4096
    const int M = in_sizes[0] / K;          // 4096

    unsigned* amaxs = (unsigned*)d_ws;
    uint8_t* qin = (uint8_t*)d_ws + 256;
    uint8_t* qw  = qin + (size_t)M * K;

    const int n4i = M * K / 4;
    const int n4w = N * K / 4;
    const int nb_i = 768, nb_w = 2048;

    init_kernel<<<1, 64, 0, stream>>>(amaxs);
    amax2_kernel<<<nb_i + nb_w, 256, 0, stream>>>(
        (const float4*)inp, n4i, (const float4*)wgt, n4w, nb_i, amaxs);
    quant2_kernel<<<nb_i + nb_w, 256, 0, stream>>>(
        (const float4*)inp, n4i, (const float4*)wgt, n4w, nb_i, amaxs,
        (unsigned*)qin, (unsigned*)qw);

    const int grid = (M >> 8) * (N >> 8);   // 16 * 43 = 688 (mult of 8)
    gemm_fp8<<<grid, 512, 0, stream>>>(qin, qw, bias, amaxs, out, M, N, K);
}